// Round 9
// baseline (416.126 us; speedup 1.0000x reference)
//
#include <hip/hip_runtime.h>

// RelGCN round 9: barrier-free K-loop (wave-private LDS A-staging) + k-split
// grid for 2x TLP.
//   prep  : hbf[r] = bf16(in @ W[r] + b[r])  fragment-swizzled   (verified)
//   gemm  : part[kh] = sum_{r,k in half} adj[r] @ hbf[r]   (f32 partials)
//           grid 1024 = 512 row-blocks x 2 k-halves, 4 waves, NO barrier in
//           K-loop: each wave stages only its own 64-k slice to private LDS,
//           depth-3 register rotation for global->LDS, B direct from L2.
//   finish: out = tanh(part[0] + part[1])

#define NN 8192
#define WSTR 68  // wave-private LDS row stride (floats): 64 + 4 pad

typedef __attribute__((ext_vector_type(4))) float float4v;
typedef __attribute__((ext_vector_type(8))) short short8v;

__device__ inline unsigned short f2bf(float f) {
  unsigned int u = __builtin_bit_cast(unsigned int, f);
  return (unsigned short)((u + 0x7FFFu + ((u >> 16) & 1u)) >> 16);  // RNE
}

// grid = 3*1024; hbf[((r*1024 + m/8)*64 + j)*8 + (m&7)] = bf16(h[r][m][j])
__global__ __launch_bounds__(256) void prep(
    const float* __restrict__ in, const float* __restrict__ W,
    const float* __restrict__ b, unsigned short* __restrict__ hbf) {
  __shared__ float Ws[64 * 64];
  __shared__ float xs[8 * 64];
  const int tid = threadIdx.x;
  const int r = blockIdx.x >> 10;
  const int kb = blockIdx.x & 1023;
#pragma unroll
  for (int i = 0; i < 16; ++i) Ws[tid + i * 256] = W[r * 4096 + tid + i * 256];
  xs[tid] = in[(size_t)kb * 512 + tid];
  xs[tid + 256] = in[(size_t)kb * 512 + 256 + tid];
  __syncthreads();
#pragma unroll
  for (int idx = tid; idx < 512; idx += 256) {
    const int ml = idx >> 6;
    const int j = idx & 63;
    float acc = b[r * 64 + j];
#pragma unroll
    for (int f = 0; f < 64; ++f) acc += xs[ml * 64 + f] * Ws[f * 64 + j];
    hbf[((size_t)((r * 1024 + kb) * 64 + j)) * 8 + ml] = f2bf(acc);
  }
}

// grid = 1024: mb = bid>>1 (16 rows), kh = bid&1 (k half). 48 tiles of 256-k.
__global__ __launch_bounds__(256) void gemm_mfma(
    const float* __restrict__ adj, const unsigned short* __restrict__ hbf,
    float* __restrict__ part) {
  __shared__ float lds[8 * 16 * WSTR];  // 4 waves x 2 private bufs, 34.8 KB
  const int tid = threadIdx.x;
  const int w = tid >> 6;
  const int l = tid & 63;
  const int lrow = l & 15;
  const int lk = l >> 4;
  const int mb = blockIdx.x >> 1;
  const int kh = blockIdx.x & 1;

  // staging map (wave-private 64-k slice): lane -> (row, 16B seg)
  const int srow = l >> 2;   // 0..15
  const int sseg = l & 3;    // 0..3
  const float* arow =
      adj + (size_t)(mb * 16 + srow) * NN + w * 64 + sseg * 4;
  float* wbuf0 = lds + (w * 2) * 16 * WSTR;
  float* wbuf1 = wbuf0 + 16 * WSTR;

  float4v acc0 = {0.f, 0.f, 0.f, 0.f}, acc1 = acc0, acc2 = acc0, acc3 = acc0;
  float4v p0, p1, p2, p3, q0, q1, q2, q3;  // two rotating GLOAD slots

  // tile tt (0..47): r = tt>>4, tpos = (tt&15) + kh*16, k-base = tpos*256
#define TOFF(TT) \
  (((size_t)((TT) >> 4) << 26) + (size_t)((((TT) & 15) + kh * 16) << 8))

#define GLOAD(TT, G0, G1, G2, G3)                                              \
  do {                                                                         \
    const float* pa_ = arow + TOFF(TT);                                        \
    G0 = *(const float4v*)(pa_);                                               \
    G1 = *(const float4v*)(pa_ + 16);                                          \
    G2 = *(const float4v*)(pa_ + 32);                                          \
    G3 = *(const float4v*)(pa_ + 48);                                          \
  } while (0)

#define DSWRITE(BUF, G0, G1, G2, G3)                                           \
  do {                                                                         \
    float* p_ = (BUF) + srow * WSTR + sseg * 4;                                \
    *(float4v*)(p_) = G0;                                                      \
    *(float4v*)(p_ + 16) = G1;                                                 \
    *(float4v*)(p_ + 32) = G2;                                                 \
    *(float4v*)(p_ + 48) = G3;                                                 \
  } while (0)

  GLOAD(0, p0, p1, p2, p3);
  DSWRITE(wbuf0, p0, p1, p2, p3);
  GLOAD(1, q0, q1, q2, q3);

#pragma unroll 1
  for (int tt = 0; tt < 48; ++tt) {
    const int r_ = tt >> 4;
    const int tpos = (tt & 15) + kh * 16;
    // B loads for this tile (L2-resident hbf), issued first
    const int mm0 = (tpos << 8) + w * 64;
    const unsigned short* pb0 =
        hbf + (size_t)(r_ * 1024 + (mm0 >> 3) + lk) * 512 + lrow * 8;
    const short8v b00 = *(const short8v*)(pb0);
    const short8v b01 = *(const short8v*)(pb0 + 128);
    const short8v b02 = *(const short8v*)(pb0 + 256);
    const short8v b03 = *(const short8v*)(pb0 + 384);
    const unsigned short* pb1 = pb0 + 4 * 512;  // +32 k
    const short8v b10 = *(const short8v*)(pb1);
    const short8v b11 = *(const short8v*)(pb1 + 128);
    const short8v b12 = *(const short8v*)(pb1 + 256);
    const short8v b13 = *(const short8v*)(pb1 + 384);

    // issue tile tt+2 into the slot whose tile was already committed
    if (tt + 2 < 48) {
      if (tt & 1) GLOAD(tt + 2, q0, q1, q2, q3);
      else        GLOAD(tt + 2, p0, p1, p2, p3);
    }

    // compute tile tt from this wave's private buf (parity tt)
    const float* cb = (tt & 1) ? wbuf1 : wbuf0;
    {
      const float* ap = cb + lrow * WSTR + lk * 8;  // chunk 0
      const float4v a0 = *(const float4v*)ap;
      const float4v a1 = *(const float4v*)(ap + 4);
      short8v av;
      av[0] = (short)f2bf(a0[0]); av[1] = (short)f2bf(a0[1]);
      av[2] = (short)f2bf(a0[2]); av[3] = (short)f2bf(a0[3]);
      av[4] = (short)f2bf(a1[0]); av[5] = (short)f2bf(a1[1]);
      av[6] = (short)f2bf(a1[2]); av[7] = (short)f2bf(a1[3]);
      acc0 = __builtin_amdgcn_mfma_f32_16x16x32_bf16(av, b00, acc0, 0, 0, 0);
      acc1 = __builtin_amdgcn_mfma_f32_16x16x32_bf16(av, b01, acc1, 0, 0, 0);
      acc2 = __builtin_amdgcn_mfma_f32_16x16x32_bf16(av, b02, acc2, 0, 0, 0);
      acc3 = __builtin_amdgcn_mfma_f32_16x16x32_bf16(av, b03, acc3, 0, 0, 0);
    }
    {
      const float* ap = cb + lrow * WSTR + 32 + lk * 8;  // chunk 1
      const float4v a0 = *(const float4v*)ap;
      const float4v a1 = *(const float4v*)(ap + 4);
      short8v av;
      av[0] = (short)f2bf(a0[0]); av[1] = (short)f2bf(a0[1]);
      av[2] = (short)f2bf(a0[2]); av[3] = (short)f2bf(a0[3]);
      av[4] = (short)f2bf(a1[0]); av[5] = (short)f2bf(a1[1]);
      av[6] = (short)f2bf(a1[2]); av[7] = (short)f2bf(a1[3]);
      acc0 = __builtin_amdgcn_mfma_f32_16x16x32_bf16(av, b10, acc0, 0, 0, 0);
      acc1 = __builtin_amdgcn_mfma_f32_16x16x32_bf16(av, b11, acc1, 0, 0, 0);
      acc2 = __builtin_amdgcn_mfma_f32_16x16x32_bf16(av, b12, acc2, 0, 0, 0);
      acc3 = __builtin_amdgcn_mfma_f32_16x16x32_bf16(av, b13, acc3, 0, 0, 0);
    }

    // commit tile tt+1 into the buf of parity tt+1 (wave-private, no barrier)
    if (tt + 1 < 48) {
      float* nb = (tt & 1) ? wbuf0 : wbuf1;
      if (tt & 1) DSWRITE(nb, p0, p1, p2, p3);
      else        DSWRITE(nb, q0, q1, q2, q3);
    }
  }
#undef GLOAD
#undef DSWRITE
#undef TOFF

  // cross-wave reduce (red aliases the wave bufs -> barrier first)
  __syncthreads();
  float* red = lds;
#pragma unroll
  for (int q = 0; q < 4; ++q) {
    red[w * 1024 + (lk * 4 + q) * 64 + 0 + lrow] = acc0[q];
    red[w * 1024 + (lk * 4 + q) * 64 + 16 + lrow] = acc1[q];
    red[w * 1024 + (lk * 4 + q) * 64 + 32 + lrow] = acc2[q];
    red[w * 1024 + (lk * 4 + q) * 64 + 48 + lrow] = acc3[q];
  }
  __syncthreads();
#pragma unroll
  for (int idx = tid; idx < 1024; idx += 256) {
    const float s = red[idx] + red[1024 + idx] + red[2048 + idx] + red[3072 + idx];
    part[(size_t)kh * (8192 * 64) + (size_t)mb * 1024 + idx] = s;
  }
}

__global__ __launch_bounds__(256) void finish_tanh(
    const float* __restrict__ part, float* __restrict__ dst) {
  const int i = blockIdx.x * 256 + threadIdx.x;
  dst[i] = tanhf(part[i] + part[i + 8192 * 64]);
}

__global__ __launch_bounds__(256) void fill_sentinel(float* __restrict__ dst) {
  dst[blockIdx.x * 256 + threadIdx.x] = 7.0f;
}

extern "C" void kernel_launch(void* const* d_in, const int* in_sizes, int n_in,
                              void* d_out, int out_size, void* d_ws, size_t ws_size,
                              hipStream_t stream) {
  const float* x   = (const float*)d_in[0];
  const float* adj = (const float*)d_in[1];
  const float* W1  = (const float*)d_in[2];
  const float* b1  = (const float*)d_in[3];
  const float* W2  = (const float*)d_in[4];
  const float* b2  = (const float*)d_in[5];
  float* out = (float*)d_out;

  const size_t HBF_B  = (size_t)3 * 8192 * 64 * 2;  // 3 MB
  const size_t T_B    = (size_t)8192 * 64 * 4;      // 2 MB
  const size_t PART_B = (size_t)2 * 8192 * 64 * 4;  // 4 MB
  if (ws_size < HBF_B + T_B + PART_B) {
    fill_sentinel<<<2048, 256, 0, stream>>>(out);
    return;
  }
  unsigned short* hbf = (unsigned short*)d_ws;
  float* t    = (float*)((char*)d_ws + HBF_B);
  float* prt  = (float*)((char*)d_ws + HBF_B + T_B);

  // layer 1
  prep<<<3 * 1024, 256, 0, stream>>>(x, W1, b1, hbf);
  gemm_mfma<<<1024, 256, 0, stream>>>(adj, hbf, prt);
  finish_tanh<<<2048, 256, 0, stream>>>(prt, t);
  // layer 2
  prep<<<3 * 1024, 256, 0, stream>>>(t, W2, b2, hbf);
  gemm_mfma<<<1024, 256, 0, stream>>>(adj, hbf, prt);
  finish_tanh<<<2048, 256, 0, stream>>>(prt, out);
}

// Round 10
// 379.439 us; speedup vs baseline: 1.0967x; 1.0967x over previous
//
#include <hip/hip_runtime.h>

// RelGCN round 10: r8 skeleton + write-early LDS pipeline + TK=512 + nontemporal
// adj loads.
//   prep : hbf[r] = bf16(in @ W[r] + b[r])  fragment-swizzled   (verified)
//   gemm : out = tanh( sum_{r,k} adj[r] @ hbf[r] )   [f32 out]
//          grid 512 x 4 waves, 16 rows/block, 48 tiles of 512-k.
//          Tile t: B-loads(t) | DSWRITE A(t+1) (loaded last tile -> no stall) |
//          GLOAD A(t+2) (nt) | 16 MFMA | barrier.  A-use distance = full tile.

#define NN 8192
#define TS 516  // LDS row stride (floats): 512 + 4 (16B-aligned, bank-spread)

typedef __attribute__((ext_vector_type(4))) float float4v;
typedef __attribute__((ext_vector_type(8))) short short8v;

__device__ inline unsigned short f2bf(float f) {
  unsigned int u = __builtin_bit_cast(unsigned int, f);
  return (unsigned short)((u + 0x7FFFu + ((u >> 16) & 1u)) >> 16);  // RNE
}

// grid = 3*1024; hbf[((r*1024 + m/8)*64 + j)*8 + (m&7)] = bf16(h[r][m][j])
__global__ __launch_bounds__(256) void prep(
    const float* __restrict__ in, const float* __restrict__ W,
    const float* __restrict__ b, unsigned short* __restrict__ hbf) {
  __shared__ float Ws[64 * 64];
  __shared__ float xs[8 * 64];
  const int tid = threadIdx.x;
  const int r = blockIdx.x >> 10;
  const int kb = blockIdx.x & 1023;
#pragma unroll
  for (int i = 0; i < 16; ++i) Ws[tid + i * 256] = W[r * 4096 + tid + i * 256];
  xs[tid] = in[(size_t)kb * 512 + tid];
  xs[tid + 256] = in[(size_t)kb * 512 + 256 + tid];
  __syncthreads();
#pragma unroll
  for (int idx = tid; idx < 512; idx += 256) {
    const int ml = idx >> 6;
    const int j = idx & 63;
    float acc = b[r * 64 + j];
#pragma unroll
    for (int f = 0; f < 64; ++f) acc += xs[ml * 64 + f] * Ws[f * 64 + j];
    hbf[((size_t)((r * 1024 + kb) * 64 + j)) * 8 + ml] = f2bf(acc);
  }
}

__global__ __launch_bounds__(256) void gemm_mfma(
    const float* __restrict__ adj, const unsigned short* __restrict__ hbf,
    float* __restrict__ out) {
  __shared__ float lds[2 * 16 * TS];  // 66 KB: two 16x512 A tiles
  float* buf0 = lds;
  float* buf1 = lds + 16 * TS;
  const int tid = threadIdx.x;
  const int w = tid >> 6;
  const int l = tid & 63;
  const int lrow = l & 15;
  const int lk = l >> 4;
  const int mb = blockIdx.x;

  // staging map: thread -> (row, 16B seg); instr i covers 16 rows x 256B runs
  const int srow = tid >> 4;
  const int sseg = tid & 15;
  const float* arow = adj + (size_t)(mb * 16 + srow) * NN + sseg * 4;

  float4v acc0 = {0.f, 0.f, 0.f, 0.f}, acc1 = acc0, acc2 = acc0, acc3 = acc0;
  float4v P0, P1, P2, P3, P4, P5, P6, P7, Q0, Q1, Q2, Q3, Q4, Q5, Q6, Q7;

// tile T (0..47): r = T>>4, within-rel k0 = (T&15)*512
#define TOFF(T) (((size_t)((T) >> 4) << 26) + ((size_t)((T) & 15) << 9))

#define GLOAD(T, S)                                                            \
  do {                                                                         \
    const float* pa_ = arow + TOFF(T);                                         \
    S##0 = __builtin_nontemporal_load((const float4v*)(pa_));                  \
    S##1 = __builtin_nontemporal_load((const float4v*)(pa_ + 64));             \
    S##2 = __builtin_nontemporal_load((const float4v*)(pa_ + 128));            \
    S##3 = __builtin_nontemporal_load((const float4v*)(pa_ + 192));            \
    S##4 = __builtin_nontemporal_load((const float4v*)(pa_ + 256));            \
    S##5 = __builtin_nontemporal_load((const float4v*)(pa_ + 320));            \
    S##6 = __builtin_nontemporal_load((const float4v*)(pa_ + 384));            \
    S##7 = __builtin_nontemporal_load((const float4v*)(pa_ + 448));            \
  } while (0)

#define DSWRITE(BUF, S)                                                        \
  do {                                                                         \
    float* p_ = (BUF) + srow * TS + sseg * 4;                                  \
    *(float4v*)(p_) = S##0;                                                    \
    *(float4v*)(p_ + 64) = S##1;                                               \
    *(float4v*)(p_ + 128) = S##2;                                              \
    *(float4v*)(p_ + 192) = S##3;                                              \
    *(float4v*)(p_ + 256) = S##4;                                              \
    *(float4v*)(p_ + 320) = S##5;                                              \
    *(float4v*)(p_ + 384) = S##6;                                              \
    *(float4v*)(p_ + 448) = S##7;                                              \
  } while (0)

#define DO_CHUNK(CUR, CC, B0, B1, B2, B3)                                      \
  do {                                                                         \
    const float* ap_ = (CUR) + lrow * TS + (w * 4 + (CC)) * 32 + lk * 8;       \
    const float4v a0_ = *(const float4v*)ap_;                                  \
    const float4v a1_ = *(const float4v*)(ap_ + 4);                            \
    short8v av_;                                                               \
    av_[0] = (short)f2bf(a0_[0]); av_[1] = (short)f2bf(a0_[1]);                \
    av_[2] = (short)f2bf(a0_[2]); av_[3] = (short)f2bf(a0_[3]);                \
    av_[4] = (short)f2bf(a1_[0]); av_[5] = (short)f2bf(a1_[1]);                \
    av_[6] = (short)f2bf(a1_[2]); av_[7] = (short)f2bf(a1_[3]);                \
    acc0 = __builtin_amdgcn_mfma_f32_16x16x32_bf16(av_, B0, acc0, 0, 0, 0);    \
    acc1 = __builtin_amdgcn_mfma_f32_16x16x32_bf16(av_, B1, acc1, 0, 0, 0);    \
    acc2 = __builtin_amdgcn_mfma_f32_16x16x32_bf16(av_, B2, acc2, 0, 0, 0);    \
    acc3 = __builtin_amdgcn_mfma_f32_16x16x32_bf16(av_, B3, acc3, 0, 0, 0);    \
  } while (0)

// wave w handles chunks w*4..w*4+3 of the 16 chunks (32-k each) in the tile.
#define TILE(T, CBUF, WBUF, WS, LS)                                            \
  do {                                                                         \
    const int rr_ = (T) >> 4;                                                  \
    const unsigned short* pbb_ =                                               \
        hbf + ((size_t)(rr_ * 1024 + ((T) & 15) * 64 + w * 16 + lk) * 512) +   \
        lrow * 8;                                                              \
    const short8v B00 = *(const short8v*)(pbb_);                               \
    const short8v B01 = *(const short8v*)(pbb_ + 128);                         \
    const short8v B02 = *(const short8v*)(pbb_ + 256);                         \
    const short8v B03 = *(const short8v*)(pbb_ + 384);                         \
    const short8v B10 = *(const short8v*)(pbb_ + 2048);                        \
    const short8v B11 = *(const short8v*)(pbb_ + 2176);                        \
    const short8v B12 = *(const short8v*)(pbb_ + 2304);                        \
    const short8v B13 = *(const short8v*)(pbb_ + 2432);                        \
    const short8v B20 = *(const short8v*)(pbb_ + 4096);                        \
    const short8v B21 = *(const short8v*)(pbb_ + 4224);                        \
    const short8v B22 = *(const short8v*)(pbb_ + 4352);                        \
    const short8v B23 = *(const short8v*)(pbb_ + 4480);                        \
    const short8v B30 = *(const short8v*)(pbb_ + 6144);                        \
    const short8v B31 = *(const short8v*)(pbb_ + 6272);                        \
    const short8v B32 = *(const short8v*)(pbb_ + 6400);                        \
    const short8v B33 = *(const short8v*)(pbb_ + 6528);                        \
    if ((T) + 1 < 48) DSWRITE(WBUF, WS);                                       \
    if ((T) + 2 < 48) GLOAD((T) + 2, LS);                                      \
    DO_CHUNK(CBUF, 0, B00, B01, B02, B03);                                     \
    DO_CHUNK(CBUF, 1, B10, B11, B12, B13);                                     \
    DO_CHUNK(CBUF, 2, B20, B21, B22, B23);                                     \
    DO_CHUNK(CBUF, 3, B30, B31, B32, B33);                                     \
    __syncthreads();                                                           \
  } while (0)

  // prologue: A(0) -> buf0, A(1) held in Q
  GLOAD(0, P);
  DSWRITE(buf0, P);
  GLOAD(1, Q);
  __syncthreads();

#pragma unroll 1
  for (int tt = 0; tt < 48; tt += 2) {
    TILE(tt, buf0, buf1, Q, P);      // even: compute buf0, write A(tt+1), load A(tt+2)->P
    TILE(tt + 1, buf1, buf0, P, Q);  // odd : compute buf1, write A(tt+2), load A(tt+3)->Q
  }
#undef TILE
#undef DO_CHUNK
#undef DSWRITE
#undef GLOAD
#undef TOFF

  // cross-wave reduce + tanh (red aliases lds; compute is done)
  float* red = lds;
#pragma unroll
  for (int q = 0; q < 4; ++q) {
    red[w * 1024 + (lk * 4 + q) * 64 + 0 + lrow] = acc0[q];
    red[w * 1024 + (lk * 4 + q) * 64 + 16 + lrow] = acc1[q];
    red[w * 1024 + (lk * 4 + q) * 64 + 32 + lrow] = acc2[q];
    red[w * 1024 + (lk * 4 + q) * 64 + 48 + lrow] = acc3[q];
  }
  __syncthreads();
#pragma unroll
  for (int idx = tid; idx < 1024; idx += 256) {
    const float s = red[idx] + red[1024 + idx] + red[2048 + idx] + red[3072 + idx];
    out[(size_t)mb * 1024 + idx] = tanhf(s);
  }
}

__global__ __launch_bounds__(256) void fill_sentinel(float* __restrict__ dst) {
  dst[blockIdx.x * 256 + threadIdx.x] = 7.0f;
}

extern "C" void kernel_launch(void* const* d_in, const int* in_sizes, int n_in,
                              void* d_out, int out_size, void* d_ws, size_t ws_size,
                              hipStream_t stream) {
  const float* x   = (const float*)d_in[0];
  const float* adj = (const float*)d_in[1];
  const float* W1  = (const float*)d_in[2];
  const float* b1  = (const float*)d_in[3];
  const float* W2  = (const float*)d_in[4];
  const float* b2  = (const float*)d_in[5];
  float* out = (float*)d_out;

  const size_t HBF_B = (size_t)3 * 8192 * 64 * 2;  // 3 MB
  const size_t T_B   = (size_t)8192 * 64 * 4;      // 2 MB
  if (ws_size < HBF_B + T_B) {
    fill_sentinel<<<2048, 256, 0, stream>>>(out);
    return;
  }
  unsigned short* hbf = (unsigned short*)d_ws;
  float* t = (float*)((char*)d_ws + HBF_B);

  // layer 1
  prep<<<3 * 1024, 256, 0, stream>>>(x, W1, b1, hbf);
  gemm_mfma<<<512, 256, 0, stream>>>(adj, hbf, t);
  // layer 2
  prep<<<3 * 1024, 256, 0, stream>>>(t, W2, b2, hbf);
  gemm_mfma<<<512, 256, 0, stream>>>(adj, hbf, out);
}